// Round 10
// baseline (286.708 us; speedup 1.0000x reference)
//
#include <hip/hip_runtime.h>
#include <hip/hip_bf16.h>
#include <cstdint>

#define T_DIM 2048
#define C_DIM 256
#define BS 8
#define NPTS (BS * T_DIM)
#define KNB 10

typedef __bf16 bf16x8 __attribute__((ext_vector_type(8)));
typedef float f32x4 __attribute__((ext_vector_type(4)));
typedef unsigned long long u64;

#define AS1 __attribute__((address_space(1)))
#define AS3 __attribute__((address_space(3)))

__device__ __forceinline__ unsigned short f2bf_rn(float f) {
  unsigned u = __float_as_uint(f);
  unsigned r = (u + 0x7FFFu + ((u >> 16) & 1u)) >> 16;
  return (unsigned short)r;
}
__device__ __forceinline__ float bfbits2f(unsigned short h) {
  return __uint_as_float((unsigned)h << 16);
}
__device__ __forceinline__ __bf16 bfbits(unsigned short h) {
  return __builtin_bit_cast(__bf16, h);
}

// pinned dif computation: identical instruction sequence at every use site.
__device__ __forceinline__ unsigned key_hi(float sqi, float sqj, float gv) {
  float dif = __fmaf_rn(-2.0f, gv, __fadd_rn(sqi, sqj));
  unsigned u = __float_as_uint(dif);
  return (u & 0x80000000u) ? ~u : (u | 0x80000000u);
}

// ---- stage a 128x64 bf16 tile into XOR-swizzled LDS via global_load_lds ----
__device__ __forceinline__ void stage_tile(const __bf16* __restrict__ src, size_t row0,
                                           int ld, int k0, __bf16* lds, int w, int l) {
  int kofs = ((l & 7) ^ (l >> 3)) * 8;
  const __bf16* g0 = src + (row0 + (size_t)(l >> 3)) * ld + k0 + kofs;
  __bf16* lbase = lds + (size_t)(w * 4) * 512;
#pragma unroll
  for (int q4 = 0; q4 < 4; ++q4) {
    __builtin_amdgcn_global_load_lds((AS1 void*)(g0 + (size_t)(w * 4 + q4) * 8 * ld),
                                     (AS3 void*)(lbase + q4 * 512), 16, 0, 0);
  }
}

// ---- stage a 64x64 bf16 tile (row panel) ----
__device__ __forceinline__ void stage_tile64(const __bf16* __restrict__ src, size_t row0,
                                             int k0, __bf16* lds, int w, int l) {
  int kofs = ((l & 7) ^ (l >> 3)) * 8;
  const __bf16* g0 = src + (row0 + (size_t)(l >> 3)) * C_DIM + k0 + kofs;
  __bf16* lbase = lds + (size_t)(w * 2) * 512;
#pragma unroll
  for (int q4 = 0; q4 < 2; ++q4) {
    __builtin_amdgcn_global_load_lds((AS1 void*)(g0 + (size_t)(w * 2 + q4) * 8 * C_DIM),
                                     (AS3 void*)(lbase + q4 * 512), 16, 0, 0);
  }
}

// conv im2col staging: K=768 = 3 taps x 256
__device__ __forceinline__ void stage_tile_conv(const __bf16* __restrict__ src, int m0,
                                                int k0in, const __bf16* __restrict__ zp,
                                                __bf16* lds, int w, int l) {
  int tap = k0in >> 8;
  int kshift = tap - 1;
  int k0 = k0in & 255;
  int kofs = ((l & 7) ^ (l >> 3)) * 8;
  int mb = m0 & (T_DIM - 1);
#pragma unroll
  for (int q4 = 0; q4 < 4; ++q4) {
    int q = w * 4 + q4;
    int row = q * 8 + (l >> 3);
    int t = mb + row + kshift;
    const __bf16* g = ((unsigned)t < (unsigned)T_DIM)
                          ? (src + (size_t)(m0 + row + kshift) * C_DIM + k0 + kofs)
                          : (zp + kofs);
    __builtin_amdgcn_global_load_lds((AS1 void*)g, (AS3 void*)(lds + q * 512), 16, 0, 0);
  }
}

__device__ __forceinline__ bf16x8 read_frag(const __bf16* lds, int t16, int ks, int l) {
  int row = t16 * 16 + (l & 15);
  int kb = ks * 64 + ((l >> 4) << 4);
  int byte = row * 128 + (kb ^ ((row & 7) << 4));
  return *(const bf16x8*)((const char*)lds + byte);
}

// ---------------- transpose + hi/lo bf16 split ----------------
__global__ __launch_bounds__(256) void k_transpose_split(const float* __restrict__ x,
                                                         __bf16* __restrict__ Fh,
                                                         __bf16* __restrict__ Fl) {
  __shared__ float tile[32][33];
  int b = blockIdx.z;
  int t0 = blockIdx.x * 32;
  int c0 = blockIdx.y * 32;
  int tx = threadIdx.x & 31, ty = threadIdx.x >> 5;
  const float* xb = x + (size_t)b * C_DIM * T_DIM;
#pragma unroll
  for (int r = 0; r < 4; ++r) {
    int c = c0 + ty + 8 * r;
    tile[ty + 8 * r][tx] = xb[(size_t)c * T_DIM + t0 + tx];
  }
  __syncthreads();
#pragma unroll
  for (int r = 0; r < 4; ++r) {
    int t = t0 + ty + 8 * r;
    float v = tile[tx][ty + 8 * r];
    unsigned short hb = f2bf_rn(v);
    float lo = v - bfbits2f(hb);
    size_t o = ((size_t)b * T_DIM + t) * C_DIM + c0 + tx;
    Fh[o] = bfbits(hb);
    Fl[o] = bfbits(f2bf_rn(lo));
  }
}

// ---------------- sq[n] = sum_c (hi+lo)^2 ----------------
__global__ __launch_bounds__(256) void k_sq(const __bf16* __restrict__ Fh,
                                            const __bf16* __restrict__ Fl,
                                            float* __restrict__ sq) {
  int n = blockIdx.x * 4 + (threadIdx.x >> 6);
  int lane = threadIdx.x & 63;
  ushort4 hv = ((const ushort4*)Fh)[(size_t)n * 64 + lane];
  ushort4 lv = ((const ushort4*)Fl)[(size_t)n * 64 + lane];
  float s = 0.f;
  {
    float v;
    v = bfbits2f(hv.x) + bfbits2f(lv.x); s = fmaf(v, v, s);
    v = bfbits2f(hv.y) + bfbits2f(lv.y); s = fmaf(v, v, s);
    v = bfbits2f(hv.z) + bfbits2f(lv.z); s = fmaf(v, v, s);
    v = bfbits2f(hv.w) + bfbits2f(lv.w); s = fmaf(v, v, s);
  }
#pragma unroll
  for (int d = 1; d < 64; d <<= 1) s += __shfl_xor(s, d, 64);
  if (lane == 0) sq[n] = s;
}

// u64 minmax helper ops are written inline below (branchless ternaries).

// ---------------- FUSED gram + top-10: streaming, gram never hits HBM ----------------
// Block = 64 rows of one batch; streams 16 chunks of 128 candidates.
// Swapped MFMA (cand as A-operand, row as B-operand) => D[cand][row]; lane l serves
// row (l&15) of its wave's 16-row tile; its cands per chunk = j*16 + (l>>4)*4 + r.
// Pass order per ks preserves original gram rounding: candhi*rowhi, candhi*rowlo,
// candlo*rowhi (products commute; k-order fixed) => dif values match R9.
// Per lane: chunk min-4 (exact) merged into running min-8 with exact ejection
// tracking. Flag row iff min(ejections, chunk 4th-smallest bounds) < theta.
__global__ __launch_bounds__(256, 1) void k_gramtopk(const __bf16* __restrict__ Fh,
                                                     const __bf16* __restrict__ Fl,
                                                     const float* __restrict__ sq,
                                                     int* __restrict__ idxo,
                                                     float* __restrict__ wo,
                                                     int* __restrict__ fixlist,
                                                     int* __restrict__ fixcount) {
  __shared__ __bf16 Bh[128 * 64], Bl[128 * 64];   // cand tiles (hi/lo), 16KB each
  __shared__ __bf16 Rh[64 * 64], Rl[64 * 64];     // row tiles (hi/lo), 8KB each
  __shared__ float sqc[128];

  int b = blockIdx.y;
  int r0 = blockIdx.x * 64;
  size_t base = (size_t)b * T_DIM;
  const float* sqb = sq + base;
  int tid = threadIdx.x, w = tid >> 6, l = tid & 63;
  int g = l >> 4;
  int myrow = r0 + w * 16 + (l & 15);
  float sqi = sqb[myrow];

  u64 s0 = ~0ull, s1 = ~0ull, s2 = ~0ull, s3 = ~0ull,
      s4 = ~0ull, s5 = ~0ull, s6 = ~0ull, s7 = ~0ull;
  u64 excl = ~0ull;   // exact ejections + conservative chunk bounds

  for (int ch = 0; ch < 16; ++ch) {
    int cand0 = ch * 128;
    if (tid < 128) sqc[tid] = sqb[cand0 + tid];
    f32x4 acc[8];
#pragma unroll
    for (int j = 0; j < 8; ++j) acc[j] = {0.f, 0.f, 0.f, 0.f};

    for (int k0 = 0; k0 < C_DIM; k0 += 64) {
      stage_tile(Fh, base + cand0, C_DIM, k0, Bh, w, l);
      stage_tile(Fl, base + cand0, C_DIM, k0, Bl, w, l);
      stage_tile64(Fh, base + r0, k0, Rh, w, l);
      stage_tile64(Fl, base + r0, k0, Rl, w, l);
      __syncthreads();
#pragma unroll
      for (int ks = 0; ks < 2; ++ks) {
        bf16x8 rh = read_frag(Rh, w, ks, l);
        bf16x8 rl = read_frag(Rl, w, ks, l);
        bf16x8 cv[8];
#pragma unroll
        for (int j = 0; j < 8; ++j) cv[j] = read_frag(Bh, j, ks, l);
#pragma unroll
        for (int j = 0; j < 8; ++j)
          acc[j] = __builtin_amdgcn_mfma_f32_16x16x32_bf16(cv[j], rh, acc[j], 0, 0, 0);
#pragma unroll
        for (int j = 0; j < 8; ++j)
          acc[j] = __builtin_amdgcn_mfma_f32_16x16x32_bf16(cv[j], rl, acc[j], 0, 0, 0);
#pragma unroll
        for (int j = 0; j < 8; ++j) cv[j] = read_frag(Bl, j, ks, l);
#pragma unroll
        for (int j = 0; j < 8; ++j)
          acc[j] = __builtin_amdgcn_mfma_f32_16x16x32_bf16(cv[j], rh, acc[j], 0, 0, 0);
      }
      __syncthreads();
    }

    // ---- chunk top-k update: exact min-4 over this lane's 32 scores ----
    u64 c0 = ~0ull, c1 = ~0ull, c2 = ~0ull, c3 = ~0ull;
#pragma unroll
    for (int j = 0; j < 8; ++j) {
      f32x4 sv = *(const f32x4*)&sqc[j * 16 + (g << 2)];
#pragma unroll
      for (int r = 0; r < 4; ++r) {
        unsigned u = key_hi(sqi, sv[r], acc[j][r]);
        unsigned cand = (unsigned)(cand0 + j * 16 + (g << 2) + r);
        u64 key = ((u64)u << 32) | cand;
        u64 t1 = (key > c0) ? key : c0; c0 = (key < c0) ? key : c0;
        u64 t2 = (t1 > c1) ? t1 : c1;  c1 = (t1 < c1) ? t1 : c1;
        u64 t3 = (t2 > c2) ? t2 : c2;  c2 = (t2 < c2) ? t2 : c2;
        c3 = (t3 < c3) ? t3 : c3;
      }
    }
    // merge c0..c3 into running sorted-8, capturing exact ejections
#pragma unroll
    for (int q = 0; q < 4; ++q) {
      u64 t = (q == 0) ? c0 : (q == 1) ? c1 : (q == 2) ? c2 : c3;
      u64 hi;
      hi = (t > s0) ? t : s0; s0 = (t < s0) ? t : s0; t = hi;
      hi = (t > s1) ? t : s1; s1 = (t < s1) ? t : s1; t = hi;
      hi = (t > s2) ? t : s2; s2 = (t < s2) ? t : s2; t = hi;
      hi = (t > s3) ? t : s3; s3 = (t < s3) ? t : s3; t = hi;
      hi = (t > s4) ? t : s4; s4 = (t < s4) ? t : s4; t = hi;
      hi = (t > s5) ? t : s5; s5 = (t < s5) ? t : s5; t = hi;
      hi = (t > s6) ? t : s6; s6 = (t < s6) ? t : s6; t = hi;
      hi = (t > s7) ? t : s7; s7 = (t < s7) ? t : s7; t = hi;
      excl = (t < excl) ? t : excl;
    }
    // conservative bound for this chunk's unretained (5th+) elements
    excl = (c3 < excl) ? c3 : excl;
    __syncthreads();  // protect sqc before next chunk restage
  }

  // ---- final extraction: top-10 over 4-lane group (32 candidates) ----
  u64 win[KNB];
#pragma unroll
  for (int s = 0; s < KNB; ++s) {
    u64 m = s0;
    { u64 o = __shfl_xor(m, 16, 64); m = (o < m) ? o : m; }
    { u64 o = __shfl_xor(m, 32, 64); m = (o < m) ? o : m; }
    bool pop = (s0 == m);
    s0 = pop ? s1 : s0; s1 = pop ? s2 : s1; s2 = pop ? s3 : s2;
    s3 = pop ? s4 : s3; s4 = pop ? s5 : s4; s5 = pop ? s6 : s5;
    s6 = pop ? s7 : s6; s7 = pop ? ~0ull : s7;
    win[s] = m;
  }
  u64 theta = win[KNB - 1];

  int* idxb = idxo + base * KNB;
  float* wbp = wo + base * KNB;
#pragma unroll
  for (int s = 0; s < KNB; ++s) {
    if ((s & 3) == g) {
      int j = (int)(unsigned)(win[s] & 0xffffffffull);
      unsigned su = (unsigned)(win[s] >> 32);
      unsigned bits = (su & 0x80000000u) ? (su & 0x7fffffffu) : ~su;
      float dif = __uint_as_float(bits);
      float sqj = sqb[j];
      float num = 0.5f * (sqi + sqj - dif);
      float wv = num / (sqrtf(sqi) * sqrtf(sqj));
      idxb[(size_t)myrow * KNB + s] = j;
      wbp[(size_t)myrow * KNB + s] = wv;
    }
  }

  { u64 o = __shfl_xor(excl, 16, 64); excl = (o < excl) ? o : excl; }
  { u64 o = __shfl_xor(excl, 32, 64); excl = (o < excl) ? o : excl; }
  if (g == 0 && excl < theta) {
    int slot = atomicAdd(fixcount, 1);
    fixlist[slot] = (int)(base + myrow);
  }
}

// ---------------- FIX kernel: recompute flagged rows exactly (fp32 VALU) ----------------
__global__ __launch_bounds__(256) void k_topk_fix(const __bf16* __restrict__ Fh,
                                                  const __bf16* __restrict__ Fl,
                                                  const float* __restrict__ sq,
                                                  const int* __restrict__ fixlist,
                                                  const int* __restrict__ fixcount,
                                                  int* __restrict__ idxo,
                                                  float* __restrict__ wo) {
  __shared__ float xr[C_DIM];
  __shared__ float difs[T_DIM];
  int n = fixcount[0];
  int tid = threadIdx.x;
  for (int i = blockIdx.x; i < n; i += gridDim.x) {
    int rowg = fixlist[i];
    int b = rowg >> 11, r = rowg & (T_DIM - 1);
    const unsigned short* fh = (const unsigned short*)Fh;
    const unsigned short* fl = (const unsigned short*)Fl;
    xr[tid] = bfbits2f(fh[(size_t)rowg * C_DIM + tid]) + bfbits2f(fl[(size_t)rowg * C_DIM + tid]);
    __syncthreads();
    const float* sqb = sq + (size_t)b * T_DIM;
    float sqi = sqb[r];
#pragma unroll 2
    for (int it = 0; it < 8; ++it) {
      int j = tid + it * 256;
      const ushort4* chp = (const ushort4*)(fh + ((size_t)b * T_DIM + j) * C_DIM);
      const ushort4* clp = (const ushort4*)(fl + ((size_t)b * T_DIM + j) * C_DIM);
      float dot = 0.f;
      for (int c4 = 0; c4 < 64; ++c4) {
        ushort4 h = chp[c4];
        ushort4 lo = clp[c4];
        dot = fmaf(bfbits2f(h.x) + bfbits2f(lo.x), xr[c4 * 4 + 0], dot);
        dot = fmaf(bfbits2f(h.y) + bfbits2f(lo.y), xr[c4 * 4 + 1], dot);
        dot = fmaf(bfbits2f(h.z) + bfbits2f(lo.z), xr[c4 * 4 + 2], dot);
        dot = fmaf(bfbits2f(h.w) + bfbits2f(lo.w), xr[c4 * 4 + 3], dot);
      }
      difs[j] = __fmaf_rn(-2.0f, dot, __fadd_rn(sqi, sqb[j]));
    }
    __syncthreads();
    if (tid < 64) {
      int lane = tid;
      u64 b0 = ~0ull, b1 = ~0ull, b2 = ~0ull, b3 = ~0ull, b4 = ~0ull,
          b5 = ~0ull, b6 = ~0ull, b7 = ~0ull, b8 = ~0ull, b9 = ~0ull;
      for (int t = 0; t < 32; ++t) {
        unsigned j = (unsigned)(lane + 64 * t);
        unsigned u = __float_as_uint(difs[j]);
        u = (u & 0x80000000u) ? ~u : (u | 0x80000000u);
        u64 key = ((u64)u << 32) | j;
        if (key < b9) {
          b9 = key;
          u64 tt;
          if (b9 < b8) { tt = b8; b8 = b9; b9 = tt; }
          if (b8 < b7) { tt = b7; b7 = b8; b8 = tt; }
          if (b7 < b6) { tt = b6; b6 = b7; b7 = tt; }
          if (b6 < b5) { tt = b5; b5 = b6; b6 = tt; }
          if (b5 < b4) { tt = b4; b4 = b5; b5 = tt; }
          if (b4 < b3) { tt = b3; b3 = b4; b4 = tt; }
          if (b3 < b2) { tt = b2; b2 = b3; b3 = tt; }
          if (b2 < b1) { tt = b1; b1 = b2; b2 = tt; }
          if (b1 < b0) { tt = b0; b0 = b1; b1 = tt; }
        }
      }
      int* idxb = idxo + (size_t)b * T_DIM * KNB;
      float* wbp = wo + (size_t)b * T_DIM * KNB;
#pragma unroll
      for (int s = 0; s < KNB; ++s) {
        u64 m = b0;
#pragma unroll
        for (int d = 1; d < 64; d <<= 1) {
          u64 o = __shfl_xor(m, d, 64);
          m = (o < m) ? o : m;
        }
        u64 bal = __ballot(b0 == m);
        int leader = (int)__builtin_ctzll(bal);
        if (lane == leader) {
          b0 = b1; b1 = b2; b2 = b3; b3 = b4; b4 = b5;
          b5 = b6; b6 = b7; b7 = b8; b8 = b9; b9 = ~0ull;
        }
        if (lane == 0) {
          int j = (int)(unsigned)(m & 0xffffffffull);
          unsigned su = (unsigned)(m >> 32);
          unsigned bits = (su & 0x80000000u) ? (su & 0x7fffffffu) : ~su;
          float dif = __uint_as_float(bits);
          float sqj = sqb[j];
          float num = 0.5f * (sqi + sqj - dif);
          float wv = num / (sqrtf(sqi) * sqrtf(sqj));
          idxb[(size_t)r * KNB + s] = j;
          wbp[(size_t)r * KNB + s] = wv;
        }
      }
    }
    __syncthreads();
  }
}

// ---------------- merged bf16 GEMM dispatch: blocks 0-3 MLP, 4-5 conv ----------------
__global__ __launch_bounds__(256, 2) void k_gemm_fused(const __bf16* __restrict__ Fh,
                                                       const __bf16* __restrict__ mlpB,
                                                       const __bf16* __restrict__ wk3,
                                                       float* __restrict__ mlpout,
                                                       float* __restrict__ convout,
                                                       const __bf16* __restrict__ zp) {
  __shared__ __bf16 As[128 * 64], Bs[128 * 64];
  int bx = blockIdx.x;
  const __bf16* Bm;
  float* C;
  int N, K, conv, n0;
  if (bx < 4) {
    Bm = mlpB; C = mlpout; N = 512; K = 256; conv = 0; n0 = bx * 128;
  } else {
    Bm = wk3; C = convout; N = 256; K = 768; conv = 1; n0 = (bx - 4) * 128;
  }
  int m0 = blockIdx.y * 128;
  int tid = threadIdx.x, w = tid >> 6, l = tid & 63;
  int wr = w >> 1, wc = w & 1;
  f32x4 acc[4][4];
#pragma unroll
  for (int i = 0; i < 4; ++i)
#pragma unroll
    for (int j = 0; j < 4; ++j) acc[i][j] = {0.f, 0.f, 0.f, 0.f};

  for (int k0 = 0; k0 < K; k0 += 64) {
    if (conv)
      stage_tile_conv(Fh, m0, k0, zp, As, w, l);
    else
      stage_tile(Fh, (size_t)m0, C_DIM, k0, As, w, l);
    stage_tile(Bm, (size_t)n0, K, k0, Bs, w, l);
    __syncthreads();
#pragma unroll
    for (int ks = 0; ks < 2; ++ks) {
      bf16x8 af[4], bf_[4];
#pragma unroll
      for (int i = 0; i < 4; ++i) af[i] = read_frag(As, wr * 4 + i, ks, l);
#pragma unroll
      for (int j = 0; j < 4; ++j) bf_[j] = read_frag(Bs, wc * 4 + j, ks, l);
#pragma unroll
      for (int i = 0; i < 4; ++i)
#pragma unroll
        for (int j = 0; j < 4; ++j)
          acc[i][j] = __builtin_amdgcn_mfma_f32_16x16x32_bf16(af[i], bf_[j], acc[i][j], 0, 0, 0);
    }
    __syncthreads();
  }
#pragma unroll
  for (int i = 0; i < 4; ++i) {
    int mrow = m0 + wr * 64 + i * 16 + ((l >> 4) << 2);
#pragma unroll
    for (int j = 0; j < 4; ++j) {
      int ncol = n0 + wc * 64 + j * 16 + (l & 15);
      float* cp = C + (size_t)mrow * N + ncol;
#pragma unroll
      for (int r = 0; r < 4; ++r) cp[(size_t)r * N] = acc[i][j][r];
    }
  }
}

// ---------------- fused gmax + conv-bias + relu + pairwise maxpool + transpose ----------------
__global__ __launch_bounds__(256) void k_gfinal(const float* __restrict__ mlpout,
                                                const float* __restrict__ mlp_b,
                                                const int* __restrict__ idxo,
                                                const float* __restrict__ wo,
                                                const float* __restrict__ convb,
                                                const float* __restrict__ cb,
                                                float* __restrict__ out) {
  __shared__ float tile[32][33];
  __shared__ int sj[64][KNB];
  __shared__ float sw[64][KNB];
  int b = blockIdx.z, c0 = blockIdx.y * 32, t20 = blockIdx.x * 32;
  int tid = threadIdx.x;
  int nbase = b * T_DIM + t20 * 2;
  for (int e = tid; e < 64 * KNB; e += 256) {
    int ln = e / KNB, k = e - ln * KNB;
    sj[ln][k] = b * T_DIM + idxo[(size_t)(nbase + ln) * KNB + k];
    sw[ln][k] = wo[(size_t)(nbase + ln) * KNB + k];
  }
  __syncthreads();
  int tx = tid & 31, ty = tid >> 5;
  int c = c0 + tx;
  float bias_c = cb[c];
  float mbias = mlp_b[c];
#pragma unroll
  for (int rr = 0; rr < 4; ++rr) {
    int lt2 = ty + 8 * rr;
    float res[2];
#pragma unroll
    for (int s = 0; s < 2; ++s) {
      int ln = 2 * lt2 + s;
      int n = nbase + ln;
      float q = mlpout[(size_t)n * 512 + 256 + c] + mbias;
      float mx = -3.4e38f;
#pragma unroll
      for (int k = 0; k < KNB; ++k) {
        float v = (mlpout[(size_t)sj[ln][k] * 512 + c] + q) * sw[ln][k];
        mx = fmaxf(mx, v);
      }
      float v = convb[(size_t)n * C_DIM + c] + mx + bias_c;
      res[s] = fmaxf(v, 0.f);
    }
    tile[lt2][tx] = fmaxf(res[0], res[1]);
  }
  __syncthreads();
#pragma unroll
  for (int rr = 0; rr < 4; ++rr) {
    int cc = c0 + ty + 8 * rr;
    out[((size_t)b * C_DIM + cc) * (T_DIM / 2) + t20 + tx] = tile[tx][ty + 8 * rr];
  }
}

// ---------------- merged repack + fixcount zeroing ----------------
__global__ void k_repack(const float* __restrict__ cw, const float* __restrict__ mw,
                         __bf16* __restrict__ wk3, __bf16* __restrict__ mlpB,
                         __bf16* __restrict__ zp, int* __restrict__ fixcount) {
  int i = blockIdx.x * 256 + threadIdx.x;
  if (i == 0) fixcount[0] = 0;
  if (i < 3 * C_DIM * C_DIM) {
    int o = i / 768;
    int rem = i - o * 768;
    int tap = rem >> 8;
    int ii = rem & 255;
    wk3[i] = bfbits(f2bf_rn(cw[(size_t)o * 768 + ii * 3 + tap]));
  } else {
    int m = i - 3 * C_DIM * C_DIM;
    if (m < 512 * 256) {
      int r = m >> 8;
      int col = m & 255;
      mlpB[m] = bfbits(f2bf_rn(mw[(size_t)(r & 255) * 512 + ((r >> 8) << 8) + col]));
    }
  }
  if (blockIdx.x == 0 && threadIdx.x < 128) zp[threadIdx.x] = bfbits(0);
}

extern "C" void kernel_launch(void* const* d_in, const int* in_sizes, int n_in,
                              void* d_out, int out_size, void* d_ws, size_t ws_size,
                              hipStream_t stream) {
  const float* x = (const float*)d_in[0];
  const float* conv_w = (const float*)d_in[2];
  const float* conv_b = (const float*)d_in[3];
  const float* mlp_w = (const float*)d_in[4];
  const float* mlp_b = (const float*)d_in[5];
  float* out = (float*)d_out;

  char* ws = (char*)d_ws;
  size_t off = 0;
  auto alloc = [&](size_t bytes) -> void* {
    void* p = ws + off;
    off += (bytes + 255) & ~(size_t)255;
    return p;
  };
  __bf16* Fh = (__bf16*)alloc((size_t)NPTS * C_DIM * 2);
  __bf16* Fl = (__bf16*)alloc((size_t)NPTS * C_DIM * 2);
  float* convout = (float*)alloc((size_t)NPTS * C_DIM * 4);
  float* mlpout = (float*)alloc((size_t)NPTS * 512 * 4);
  float* sq = (float*)alloc((size_t)NPTS * 4);
  int* idxb = (int*)alloc((size_t)NPTS * KNB * 4);
  float* wb = (float*)alloc((size_t)NPTS * KNB * 4);
  int* fixlist = (int*)alloc((size_t)NPTS * 4);
  int* fixcount = (int*)alloc(256);
  __bf16* wk3 = (__bf16*)alloc((size_t)3 * C_DIM * C_DIM * 2);
  __bf16* mlpB = (__bf16*)alloc((size_t)512 * 256 * 2);
  __bf16* zp = (__bf16*)alloc(512);

  k_repack<<<dim3(1280), 256, 0, stream>>>(conv_w, mlp_w, wk3, mlpB, zp, fixcount);
  k_transpose_split<<<dim3(T_DIM / 32, C_DIM / 32, BS), 256, 0, stream>>>(x, Fh, Fl);
  k_sq<<<dim3(NPTS / 4), 256, 0, stream>>>(Fh, Fl, sq);

  // fused gram + top-10 (gram never materialized)
  k_gramtopk<<<dim3(T_DIM / 64, BS), 256, 0, stream>>>(Fh, Fl, sq, idxb, wb, fixlist, fixcount);
  k_topk_fix<<<dim3(64), 256, 0, stream>>>(Fh, Fl, sq, fixlist, fixcount, idxb, wb);

  k_gemm_fused<<<dim3(6, NPTS / 128), 256, 0, stream>>>(Fh, mlpB, wk3, mlpout, convout, zp);

  k_gfinal<<<dim3((T_DIM / 2) / 32, C_DIM / 32, BS), 256, 0, stream>>>(
      mlpout, mlp_b, idxb, wb, convout, conv_b, out);
}